// Round 1
// baseline (3639.368 us; speedup 1.0000x reference)
//
#include <hip/hip_runtime.h>

#define BB 512
#define TT 2048
#define DD 8
#define HH 64
#define GG 256  // 4*H gates

__device__ __forceinline__ float rlane(float v, int l) {
  return __int_as_float(__builtin_amdgcn_readlane(__float_as_int(v), l));
}
__device__ __forceinline__ float sigm(float x) {
  return 1.0f / (1.0f + __expf(-x));
}
__device__ __forceinline__ float tanh_fast(float x) {
  // tanh(x) = 1 - 2/(exp(2x)+1); saturates correctly at +/-inf
  return 1.0f - 2.0f / (__expf(2.0f * x) + 1.0f);
}

// One block per batch element. Thread g (0..255) owns gate row g of both
// layers' weight matrices in registers (200 VGPRs). Every wave keeps a full
// replica of h0/h1/c0/c1 (lane j holds element j), so matvec broadcasts use
// v_readlane -> SGPR-operand FMAs instead of LDS. Only activated gates go
// through LDS (parity double-buffered, 2 barriers/step).
__global__ __launch_bounds__(256, 2) void lstm2_fused(
    const float* __restrict__ x,
    const float* __restrict__ w_ih0, const float* __restrict__ w_hh0,
    const float* __restrict__ b_ih0, const float* __restrict__ b_hh0,
    const float* __restrict__ w_ih1, const float* __restrict__ w_hh1,
    const float* __restrict__ b_ih1, const float* __restrict__ b_hh1,
    const float* __restrict__ w_out, const float* __restrict__ b_out,
    float* __restrict__ out)
{
  const int b    = blockIdx.x;
  const int tid  = threadIdx.x;   // gate index g
  const int lane = tid & 63;
  const int wave = tid >> 6;      // 0:i 1:f 2:g 3:o

  __shared__ float g0buf[2][GG];
  __shared__ float g1buf[2][GG];

  // ---- load this thread's weight rows into registers (one-time) ----
  float wih0[DD], whh0[HH], wih1[HH], whh1[HH];
#pragma unroll
  for (int k = 0; k < DD; ++k) wih0[k] = w_ih0[tid * DD + k];
#pragma unroll
  for (int k = 0; k < HH; ++k) whh0[k] = w_hh0[tid * HH + k];
#pragma unroll
  for (int k = 0; k < HH; ++k) wih1[k] = w_ih1[tid * HH + k];
#pragma unroll
  for (int k = 0; k < HH; ++k) whh1[k] = w_hh1[tid * HH + k];
  const float bias0 = b_ih0[tid] + b_hh0[tid];
  const float bias1 = b_ih1[tid] + b_hh1[tid];

  // per-wave replicated state: lane j holds element j
  float h0 = 0.0f, c0 = 0.0f, h1 = 0.0f, c1 = 0.0f;
  // layer0 gate preactivation carried across steps:
  // acc0 = bias0 + Whh0 . h0[t-1]   (h0[-1]=0 -> just bias0)
  float acc0 = bias0;

  const float* xb = x + (size_t)b * TT * DD;
  float xc[DD];
#pragma unroll
  for (int k = 0; k < DD; ++k) xc[k] = xb[k];  // x[t=0]

  for (int t = 0; t < TT; ++t) {
    const int p = t & 1;

    // ---- layer 0: finish gate with x contribution ----
#pragma unroll
    for (int k = 0; k < DD; ++k) acc0 = fmaf(wih0[k], xc[k], acc0);

    // prefetch next step's x (consumed ~400 insts later)
    {
      const int tn = (t + 1 < TT) ? (t + 1) : (TT - 1);
#pragma unroll
      for (int k = 0; k < DD; ++k) xc[k] = xb[tn * DD + k];
    }

    const float a0 = (wave == 2) ? tanh_fast(acc0) : sigm(acc0);
    g0buf[p][tid] = a0;
    __syncthreads();
    {
      const float gi = g0buf[p][lane];
      const float gf = g0buf[p][HH + lane];
      const float gg = g0buf[p][2 * HH + lane];
      const float go = g0buf[p][3 * HH + lane];
      c0 = fmaf(gf, c0, gi * gg);
      h0 = go * tanh_fast(c0);
    }

    // ---- layer 1 gates + next-step layer 0 Whh part (shared h0 broadcast) ----
    float acc1  = bias1;
    float acc0n = bias0;
#pragma unroll
    for (int k = 0; k < HH; ++k) {
      const float h0k = rlane(h0, k);
      acc1  = fmaf(wih1[k], h0k, acc1);
      acc0n = fmaf(whh0[k], h0k, acc0n);
      const float h1k = rlane(h1, k);
      acc1  = fmaf(whh1[k], h1k, acc1);
    }

    const float a1 = (wave == 2) ? tanh_fast(acc1) : sigm(acc1);
    g1buf[p][tid] = a1;
    __syncthreads();
    {
      const float gi = g1buf[p][lane];
      const float gf = g1buf[p][HH + lane];
      const float gg = g1buf[p][2 * HH + lane];
      const float go = g1buf[p][3 * HH + lane];
      c1 = fmaf(gf, c1, gi * gg);
      h1 = go * tanh_fast(c1);
    }
    acc0 = acc0n;
  }

  // ---- head: out[b] = dot(h1, w_out) + b_out ----
  float v = h1 * w_out[lane];
#pragma unroll
  for (int off = 32; off; off >>= 1) v += __shfl_down(v, off);
  if (tid == 0) out[b] = v + b_out[0];
}

extern "C" void kernel_launch(void* const* d_in, const int* in_sizes, int n_in,
                              void* d_out, int out_size, void* d_ws, size_t ws_size,
                              hipStream_t stream) {
  const float* x     = (const float*)d_in[0];
  const float* w_ih0 = (const float*)d_in[1];
  const float* w_hh0 = (const float*)d_in[2];
  const float* b_ih0 = (const float*)d_in[3];
  const float* b_hh0 = (const float*)d_in[4];
  const float* w_ih1 = (const float*)d_in[5];
  const float* w_hh1 = (const float*)d_in[6];
  const float* b_ih1 = (const float*)d_in[7];
  const float* b_hh1 = (const float*)d_in[8];
  const float* w_out = (const float*)d_in[9];
  const float* b_out = (const float*)d_in[10];
  float* out = (float*)d_out;

  lstm2_fused<<<dim3(BB), dim3(256), 0, stream>>>(
      x, w_ih0, w_hh0, b_ih0, b_hh0,
      w_ih1, w_hh1, b_ih1, b_hh1,
      w_out, b_out, out);
}

// Round 2
// 3473.050 us; speedup vs baseline: 1.0479x; 1.0479x over previous
//
#include <hip/hip_runtime.h>

#define BB 512
#define TT 2048
#define DD 8
#define HH 64
#define GG 256  // 4*H gates

__device__ __forceinline__ float rlane(float v, int l) {
  return __int_as_float(__builtin_amdgcn_readlane(__float_as_int(v), l));
}
__device__ __forceinline__ float sigm(float x) {
  return 1.0f / (1.0f + __expf(-x));
}
__device__ __forceinline__ float tanh_fast(float x) {
  // tanh(x) = 1 - 2/(exp(2x)+1); saturates correctly at +/-inf
  return 1.0f - 2.0f / (__expf(2.0f * x) + 1.0f);
}
__device__ __forceinline__ float2 pk_fma(float2 a, float2 b, float2 c) {
  // hoping for v_pk_fma_f32; scalarizes harmlessly otherwise
  float2 r;
  r.x = fmaf(a.x, b.x, c.x);
  r.y = fmaf(a.y, b.y, c.y);
  return r;
}

// One block per batch element; thread g (0..255) owns gate row g of both
// layers in registers. wih1/whh0 rows are interleaved as float2 so the two
// h0-driven accumulator streams share one v_pk_fma_f32 per k.
// amdgpu_waves_per_eu(2,2) pins the allocator at 2 waves/EU (the grid is
// exactly 2 blocks/CU anyway) so the ~230-float footprint stays in VGPRs
// instead of spilling to scratch (round-1 failure mode: VGPR=108, 34 GB FETCH).
__global__ void __launch_bounds__(256)
    __attribute__((amdgpu_waves_per_eu(2, 2)))
    lstm2_fused(
        const float* __restrict__ x,
        const float* __restrict__ w_ih0, const float* __restrict__ w_hh0,
        const float* __restrict__ b_ih0, const float* __restrict__ b_hh0,
        const float* __restrict__ w_ih1, const float* __restrict__ w_hh1,
        const float* __restrict__ b_ih1, const float* __restrict__ b_hh1,
        const float* __restrict__ w_out, const float* __restrict__ b_out,
        float* __restrict__ out)
{
  const int b    = blockIdx.x;
  const int tid  = threadIdx.x;   // gate index g
  const int lane = tid & 63;
  const int wave = tid >> 6;      // 0:i 1:f 2:g 3:o

  __shared__ float g0buf[2][GG];
  __shared__ float g1buf[2][GG];

  // ---- one-time: this thread's weight rows into registers ----
  float wih0[DD];
  float2 w01[HH];   // (wih1[k], whh0[k]) interleaved -> one pk_fma per k
  float  w11[HH];   // whh1[k]
#pragma unroll
  for (int k = 0; k < DD; ++k) wih0[k] = w_ih0[tid * DD + k];
#pragma unroll
  for (int k = 0; k < HH; ++k)
    w01[k] = make_float2(w_ih1[tid * HH + k], w_hh0[tid * HH + k]);
#pragma unroll
  for (int k = 0; k < HH; ++k) w11[k] = w_hh1[tid * HH + k];
  const float bias0 = b_ih0[tid] + b_hh0[tid];
  const float bias1 = b_ih1[tid] + b_hh1[tid];

  // per-wave replicated state: lane j holds element j
  float h0 = 0.0f, c0 = 0.0f, h1 = 0.0f, c1 = 0.0f;
  // layer0 preactivation carried across steps: acc0 = bias0 + Whh0.h0[t-1]
  float acc0 = bias0;

  const float4* xb4 = reinterpret_cast<const float4*>(x + (size_t)b * TT * DD);
  float4 xa = xb4[0], xb_ = xb4[1];  // x[t=0]

  for (int t = 0; t < TT; ++t) {
    const int p = t & 1;

    // ---- layer 0: add x contribution ----
    acc0 = fmaf(wih0[0], xa.x, acc0);
    acc0 = fmaf(wih0[1], xa.y, acc0);
    acc0 = fmaf(wih0[2], xa.z, acc0);
    acc0 = fmaf(wih0[3], xa.w, acc0);
    acc0 = fmaf(wih0[4], xb_.x, acc0);
    acc0 = fmaf(wih0[5], xb_.y, acc0);
    acc0 = fmaf(wih0[6], xb_.z, acc0);
    acc0 = fmaf(wih0[7], xb_.w, acc0);

    // prefetch next step's x (consumed ~600 cycles later)
    {
      const int tn = (t + 1 < TT) ? (t + 1) : (TT - 1);
      xa  = xb4[2 * tn];
      xb_ = xb4[2 * tn + 1];
    }

    const float a0 = (wave == 2) ? tanh_fast(acc0) : sigm(acc0);
    g0buf[p][tid] = a0;
    __syncthreads();
    {
      const float gi = g0buf[p][lane];
      const float gf = g0buf[p][HH + lane];
      const float gg = g0buf[p][2 * HH + lane];
      const float go = g0buf[p][3 * HH + lane];
      c0 = fmaf(gf, c0, gi * gg);
      h0 = go * tanh_fast(c0);
    }

    // ---- layer 1 gates + next-step layer0 Whh part, h0 broadcast shared ----
    float2 accp = make_float2(bias1, bias0);  // (acc1, acc0_next)
    float acc1b = 0.0f;
#pragma unroll
    for (int k = 0; k < HH; ++k) {
      const float h0k = rlane(h0, k);
      const float h1k = rlane(h1, k);
      accp  = pk_fma(w01[k], make_float2(h0k, h0k), accp);
      acc1b = fmaf(w11[k], h1k, acc1b);
    }
    const float accg1 = accp.x + acc1b;

    const float a1 = (wave == 2) ? tanh_fast(accg1) : sigm(accg1);
    g1buf[p][tid] = a1;
    __syncthreads();
    {
      const float gi = g1buf[p][lane];
      const float gf = g1buf[p][HH + lane];
      const float gg = g1buf[p][2 * HH + lane];
      const float go = g1buf[p][3 * HH + lane];
      c1 = fmaf(gf, c1, gi * gg);
      h1 = go * tanh_fast(c1);
    }
    acc0 = accp.y;
  }

  // ---- head: out[b] = dot(h1, w_out) + b_out ----
  float v = h1 * w_out[lane];
#pragma unroll
  for (int off = 32; off; off >>= 1) v += __shfl_down(v, off);
  if (tid == 0) out[b] = v + b_out[0];
}

extern "C" void kernel_launch(void* const* d_in, const int* in_sizes, int n_in,
                              void* d_out, int out_size, void* d_ws, size_t ws_size,
                              hipStream_t stream) {
  const float* x     = (const float*)d_in[0];
  const float* w_ih0 = (const float*)d_in[1];
  const float* w_hh0 = (const float*)d_in[2];
  const float* b_ih0 = (const float*)d_in[3];
  const float* b_hh0 = (const float*)d_in[4];
  const float* w_ih1 = (const float*)d_in[5];
  const float* w_hh1 = (const float*)d_in[6];
  const float* b_ih1 = (const float*)d_in[7];
  const float* b_hh1 = (const float*)d_in[8];
  const float* w_out = (const float*)d_in[9];
  const float* b_out = (const float*)d_in[10];
  float* out = (float*)d_out;

  lstm2_fused<<<dim3(BB), dim3(256), 0, stream>>>(
      x, w_ih0, w_hh0, b_ih0, b_hh0,
      w_ih1, w_hh1, b_ih1, b_hh1,
      w_out, b_out, out);
}